// Round 11
// baseline (265.095 us; speedup 1.0000x reference)
//
#include <hip/hip_runtime.h>
#include <hip/hip_bf16.h>
#include <stdint.h>

// Problem constants (B,T,D,NH from reference)
#define NHh 16
#define Dm  1024
#define HD  64          // head dim = D/NH
#define Bb  4
#define Tt  4096
#define NCH 128         // chunks along T for the two-pass scans
#define CHL 32          // chunk length (NCH*CHL == Tt)

// GEMM tile geometry: 256x128, BK=32 -> 48KB LDS, 2 blocks/CU
#define BM 256
#define BN 128
#define BK 32
#define NKT (Dm / BK)   // 32 K-steps

using bf16 = __hip_bfloat16;
typedef __attribute__((ext_vector_type(8))) short short8;   // 8 bf16 in 4 VGPRs (MFMA A/B frag)
typedef __attribute__((ext_vector_type(4))) float f32x4;    // MFMA C/D frag

__device__ __forceinline__ float bf2f(bf16 v) { return __bfloat162float(v); }

// bf16 bits -> f32 (exact): bf16 is the high 16 bits of f32
__device__ __forceinline__ float b2f(unsigned short u) {
  union { unsigned int i; float f; } x; x.i = ((unsigned int)u) << 16; return x.f;
}

// fast reciprocal via v_rcp_f32 (~1 ulp; inputs are bf16-derived, tolerance is 1e-2)
__device__ __forceinline__ float frcp(float x) {
  float r; asm("v_rcp_f32 %0, %1" : "=v"(r) : "v"(x)); return r;
}

// async global->LDS, 16B per lane. LDS dest is wave-uniform base + lane*16;
// the GLOBAL source address is PER-LANE (must include the lane offset!).
__device__ __forceinline__ void gld_lds16(const void* g, void* l) {
  __builtin_amdgcn_global_load_lds(
      (const __attribute__((address_space(1))) unsigned int*)g,
      (__attribute__((address_space(3))) unsigned int*)l, 16, 0, 0);
}

// ======= 256x128 GEMM, BK=32, double-buffered, 2 blocks/CU (occupancy bet) ===
// C[m][n] = sum_k A[m][k] * W[n][k]  (both K-contiguous row-major, bf16).
// 512 thr = 8 waves (4M x 2N); per-wave 64x64 -> acc[4][4] (64 regs) so the
// total reg budget fits 128/wave -> 4 waves/SIMD -> 2 blocks/CU (the lever:
// cross-block wave overlap hides barrier/vmcnt stalls, m114 mechanism).
// LDS 48KB: buf x {A [256][32] 16KB | B [128][32] 8KB}.  Per K-step:
// issue 3 stage slabs (t+1) -> 8 swizzled ds_read_b128 -> 16 MFMA ->
// vmcnt(0) (stages had a full step of cover) -> one s_barrier.
// Slab layout [R][32] bf16 (64B rows): 16B chunk c of row r stored at
// c ^ ((r>>1)&3) -> frag reads are 2-way bank-aliased (free, m136).
// gld_lds writes linearly; global source per lane is inverse-swizzled:
// row = wave*16 + (lane>>2) (+128*n), elem col = 8*((lane&3)^((lane>>3)&3)).
// WRITE_S1: fuse per-32-row chunk sums of bf16(w)^2 into the epilogue.
template <bool OUT_BF16, bool WRITE_S1>
__global__ __launch_bounds__(512, 4) void gemm256(const bf16* __restrict__ A,
                                                  const bf16* __restrict__ W,
                                                  void* __restrict__ Cout,
                                                  float* __restrict__ S1,
                                                  int M, int N, int K) {
  extern __shared__ char smem[];   // 49152 B
  const int tid  = threadIdx.x;
  const int lane = tid & 63;
  const int wave = tid >> 6;       // 0..7
  // XCD-chunked swizzle: 512 blocks = 8 XCDs x 64; within a chunk, 8
  // consecutive swz share the same A-panel (bm) across all 8 bn tiles.
  const int bid = blockIdx.x;
  const int swz = (bid & 7) * 64 + (bid >> 3);
  const int bn = (swz & 7) * BN;          // N/BN = 8
  const int bm = (swz >> 3) * BM;         // M/BM = 64
  const int wm = (wave >> 1) * 64;        // 4 M bands
  const int wn = (wave & 1) * 64;         // 2 N halves
  const int quad = lane >> 4;             // 16B chunk 0..3
  const int l16  = lane & 15;

  // staging source (per lane): inverse-swizzled global address
  const int srow = wave * 16 + (lane >> 2);                    // 0..127 (+128n)
  const int scol = (((lane & 3) ^ ((lane >> 3) & 3)) << 3);    // elements

  const bf16* Abase = A + (size_t)(bm + srow) * K + scol;
  const bf16* Wbase = W + (size_t)(bn + srow) * K + scol;

  f32x4 acc[4][4] = {};

#define SLAB_A(buf, n) (smem + (buf) * 24576 + (n) * 8192 + wave * 1024)
#define SLAB_B(buf)    (smem + (buf) * 24576 + 16384 + wave * 1024)
#define STAGE_A(buf, n, k0) gld_lds16(Abase + (size_t)(n) * 128 * K + (k0), SLAB_A(buf, n))
#define STAGE_B(buf, k0)    gld_lds16(Wbase + (k0), SLAB_B(buf))
  // swizzled ds_read of one 16B frag: slab base sb, row r, chunk c
#define LD_FRAG(sb, r, c) (*(const short8*)((sb) + (size_t)(r) * 64 + ((((c) ^ (((r) >> 1) & 3))) << 4)))

  // prologue: stage step 0 into buf 0
  STAGE_A(0, 0, 0); STAGE_A(0, 1, 0); STAGE_B(0, 0);
  asm volatile("s_waitcnt vmcnt(0)" ::: "memory");
  __builtin_amdgcn_s_barrier();
  __builtin_amdgcn_sched_barrier(0);

  short8 af[4], bf8[4];
  for (int t = 0; t < NKT; t++) {
    const int buf = t & 1;
    const char* aL = smem + buf * 24576;
    const char* bL = aL + 16384;
    const int k0n = (t + 1) * BK;
    if (t + 1 < NKT) {
      STAGE_A(buf ^ 1, 0, k0n); STAGE_A(buf ^ 1, 1, k0n); STAGE_B(buf ^ 1, k0n);
    }
#pragma unroll
    for (int mi = 0; mi < 4; mi++) af[mi]  = LD_FRAG(aL, wm + mi * 16 + l16, quad);
#pragma unroll
    for (int nj = 0; nj < 4; nj++) bf8[nj] = LD_FRAG(bL, wn + nj * 16 + l16, quad);
    __builtin_amdgcn_s_setprio(1);
#pragma unroll
    for (int mi = 0; mi < 4; mi++)
#pragma unroll
      for (int nj = 0; nj < 4; nj++)
        acc[mi][nj] = __builtin_amdgcn_mfma_f32_16x16x32_bf16(af[mi], bf8[nj], acc[mi][nj], 0, 0, 0);
    __builtin_amdgcn_s_setprio(0);
    // own stage loads had a full step of cover; other block's waves hide the rest
    asm volatile("s_waitcnt vmcnt(0)" ::: "memory");
    __builtin_amdgcn_s_barrier();
    __builtin_amdgcn_sched_barrier(0);
  }

  // epilogue.  C/D layout: col = lane&15, row = (lane>>4)*4 + reg
#pragma unroll
  for (int nj = 0; nj < 4; nj++) {
    const int col = bn + wn + nj * 16 + l16;
    if constexpr (OUT_BF16) {
      float ss0 = 0.f, ss1 = 0.f;   // two 32-row chunks of this wave's 64-row band
#pragma unroll
      for (int mi = 0; mi < 4; mi++) {
        float csum = 0.f;
#pragma unroll
        for (int r = 0; r < 4; r++) {
          const int row = bm + wm + mi * 16 + quad * 4 + r;
          const bf16 hv = __float2bfloat16(acc[mi][nj][r]);
          ((bf16*)Cout)[(size_t)row * N + col] = hv;
          if constexpr (WRITE_S1) { const float fv = bf2f(hv); csum += fv * fv; }
        }
        if constexpr (WRITE_S1) { if (mi < 2) ss0 += csum; else ss1 += csum; }
      }
      if constexpr (WRITE_S1) {
        ss0 += __shfl_xor(ss0, 16, 64); ss0 += __shfl_xor(ss0, 32, 64);
        ss1 += __shfl_xor(ss1, 16, 64); ss1 += __shfl_xor(ss1, 32, 64);
        if (quad == 0) {
          const int h = col >> 6, d = col & 63;
          const int r0 = bm + wm;                    // first row of this wave's band
          const int b  = r0 >> 12;                   // / Tt
          const int c0 = (r0 & (Tt - 1)) >> 5;       // / CHL (=32)
          float* s1p = S1 + (((size_t)(b * NHh + h) * NCH) + c0) * HD + d;
          s1p[0]  = ss0;
          s1p[HD] = ss1;
        }
      }
    } else {
#pragma unroll
      for (int mi = 0; mi < 4; mi++)
#pragma unroll
        for (int r = 0; r < 4; r++) {
          const int row = bm + wm + mi * 16 + quad * 4 + r;
          ((float*)Cout)[(size_t)row * N + col] = acc[mi][nj][r];
        }
    }
  }
#undef SLAB_A
#undef SLAB_B
#undef STAGE_A
#undef STAGE_B
#undef LD_FRAG
}

// ===== prep: fused {cast x, cast W_attn, cast W_proj, phi->penalty} ==========
__global__ __launch_bounds__(256) void prep(const float* __restrict__ x,
                                            const float* __restrict__ Wa,
                                            const float* __restrict__ Wp,
                                            const float* __restrict__ phi,
                                            bf16* __restrict__ x_bf,
                                            bf16* __restrict__ Wa_bf,
                                            bf16* __restrict__ Wp_bf,
                                            float* __restrict__ penalty) {
  const int bid = blockIdx.x;
  if (bid < 1536) {
    const float* in;
    bf16* out;
    int n, nblk, b0;
    if (bid < 1024)      { in = x;  out = x_bf;  n = Bb * Tt * Dm; nblk = 1024; b0 = 0; }
    else if (bid < 1280) { in = Wa; out = Wa_bf; n = Dm * Dm;      nblk = 256;  b0 = 1024; }
    else                 { in = Wp; out = Wp_bf; n = Dm * Dm;      nblk = 256;  b0 = 1280; }
    const int stride = nblk * 256;
    for (int i = (bid - b0) * 256 + threadIdx.x; i * 4 < n; i += stride) {
      const float4 v = *(const float4*)(in + (size_t)i * 4);
      ushort4 o;
      o.x = __bfloat16_as_ushort(__float2bfloat16(v.x));
      o.y = __bfloat16_as_ushort(__float2bfloat16(v.y));
      o.z = __bfloat16_as_ushort(__float2bfloat16(v.z));
      o.w = __bfloat16_as_ushort(__float2bfloat16(v.w));
      *(ushort4*)(out + (size_t)i * 4) = o;
    }
  } else {
    const int b = bid - 1536;
    const int tid = threadIdx.x;            // 256
    const int lane = tid & 63, wid = tid >> 6;
    __shared__ float wsum[4];
    __shared__ float carry_s;
    if (tid == 0) carry_s = 0.f;
    __syncthreads();
    for (int r = 0; r < Tt / 256; r++) {
      const int t = r * 256 + tid;
      const float v = phi[b * Tt + t];
      float incl = v;
#pragma unroll
      for (int off = 1; off < 64; off <<= 1) {
        float nn = __shfl_up(incl, off, 64);
        if (lane >= off) incl += nn;
      }
      if (lane == 63) wsum[wid] = incl;
      __syncthreads();
      float woff = carry_s;
      for (int wpre = 0; wpre < wid; wpre++) woff += wsum[wpre];
      const float csum = woff + incl;
      const float mean = csum / (float)(t + 1);
      const float dphi = v - mean;
      penalty[b * Tt + t] = dphi * dphi;
      __syncthreads();
      if (tid == 0) carry_s += wsum[0] + wsum[1] + wsum[2] + wsum[3];
      __syncthreads();
    }
  }
}

// ===== fused middle (R8-best): inline S1 prefix -> tssa -> softmax -> dots ===
__global__ __launch_bounds__(256) void mid_fused(const bf16* __restrict__ w,
                                                 const float* __restrict__ S1,
                                                 const float* __restrict__ temp,
                                                 const float* __restrict__ gamma,
                                                 const float* __restrict__ penalty,
                                                 float* __restrict__ alpha_f,
                                                 float* __restrict__ S2,
                                                 float* __restrict__ SA) {
  const int c = blockIdx.x, b = blockIdx.y;
  const int tid = threadIdx.x, h = tid >> 4, l = tid & 15;
  __shared__ float sm_t[CHL][NHh + 1];
  __shared__ float sm_a[CHL][NHh + 1];
  __shared__ float sm_g[NHh], sm_tv[NHh];
  if (tid < NHh) { sm_g[tid] = gamma[tid]; sm_tv[tid] = temp[tid]; }

  // inline exclusive prefix of S1 over chunks < c, 4-deep ILP
  const float4* p4 = (const float4*)(S1 + (((size_t)(b * NHh + h) * NCH)) * HD + l * 4);
  float4 s0 = {0,0,0,0}, s1v = {0,0,0,0}, s2v = {0,0,0,0}, s3v = {0,0,0,0};
  int cc = 0;
  for (; cc + 4 <= c; cc += 4) {
    const float4 v0 = p4[(size_t)cc * 16];
    const float4 v1 = p4[(size_t)(cc + 1) * 16];
    const float4 v2 = p4[(size_t)(cc + 2) * 16];
    const float4 v3 = p4[(size_t)(cc + 3) * 16];
    s0.x += v0.x; s0.y += v0.y; s0.z += v0.z; s0.w += v0.w;
    s1v.x += v1.x; s1v.y += v1.y; s1v.z += v1.z; s1v.w += v1.w;
    s2v.x += v2.x; s2v.y += v2.y; s2v.z += v2.z; s2v.w += v2.w;
    s3v.x += v3.x; s3v.y += v3.y; s3v.z += v3.z; s3v.w += v3.w;
  }
  for (; cc < c; cc++) {
    const float4 v0 = p4[(size_t)cc * 16];
    s0.x += v0.x; s0.y += v0.y; s0.z += v0.z; s0.w += v0.w;
  }
  float a0 = s0.x + s1v.x + s2v.x + s3v.x;
  float a1 = s0.y + s1v.y + s2v.y + s3v.y;
  float a2 = s0.z + s1v.z + s2v.z + s3v.z;
  float a3 = s0.w + s1v.w + s2v.w + s3v.w;
  __syncthreads();   // sm_g/sm_tv ready

  const bf16* wp = w + ((size_t)(b * Tt + c * CHL)) * Dm + h * HD + l * 4;
  const float tv = sm_tv[h];
#pragma unroll 8
  for (int i = 0; i < CHL; i++) {
    const ushort4 v = *(const ushort4*)(wp + (size_t)i * Dm);
    const float f0 = b2f(v.x), f1 = b2f(v.y), f2 = b2f(v.z), f3 = b2f(v.w);
    const float q0 = f0 * f0, q1 = f1 * f1, q2 = f2 * f2, q3 = f3 * f3;
    a0 += q0; a1 += q1; a2 += q2; a3 += q3;
    float val = q0 * frcp(fmaxf(a0, 1e-12f)) + q1 * frcp(fmaxf(a1, 1e-12f))
              + q2 * frcp(fmaxf(a2, 1e-12f)) + q3 * frcp(fmaxf(a3, 1e-12f));
    val += __shfl_xor(val, 1, 64);
    val += __shfl_xor(val, 2, 64);
    val += __shfl_xor(val, 4, 64);
    val += __shfl_xor(val, 8, 64);
    if (l == 0) sm_t[i][h] = tv * val;
  }
  __syncthreads();

  if (tid < CHL) {
    const int t = tid;
    const float pen = penalty[(size_t)b * Tt + c * CHL + t];
    float sc[NHh];
    float mx = -1e30f;
#pragma unroll
    for (int hh = 0; hh < NHh; hh++) {
      sc[hh] = sm_t[t][hh] - sm_g[hh] * pen;
      mx = fmaxf(mx, sc[hh]);
    }
    float sum = 0.f;
#pragma unroll
    for (int hh = 0; hh < NHh; hh++) { const float e = __expf(sc[hh] - mx); sc[hh] = e; sum += e; }
    const float inv = 1.f / sum;
#pragma unroll
    for (int hh = 0; hh < NHh; hh++) sm_a[t][hh] = sc[hh] * inv;
  }
  __syncthreads();

#pragma unroll
  for (int k2 = 0; k2 < CHL / 16; k2++) {
    const int t = k2 * 16 + l;
    alpha_f[((size_t)(b * NHh + h)) * Tt + c * CHL + t] = sm_a[t][h];
  }

  float d0 = 0.f, d1 = 0.f, d2 = 0.f, d3 = 0.f, sa = 0.f;
#pragma unroll 8
  for (int i = 0; i < CHL; i++) {
    const float a = sm_a[i][h];
    const ushort4 v = *(const ushort4*)(wp + (size_t)i * Dm);
    const float f0 = b2f(v.x), f1 = b2f(v.y), f2 = b2f(v.z), f3 = b2f(v.w);
    d0 += f0 * f0 * a; d1 += f1 * f1 * a; d2 += f2 * f2 * a; d3 += f3 * f3 * a;
    sa += a;
  }
  float4 o; o.x = d0; o.y = d1; o.z = d2; o.w = d3;
  *(float4*)&S2[(((size_t)(b * NHh + h) * NCH) + c) * HD + l * 4] = o;
  if (l == 0) SA[(size_t)(b * NHh + h) * NCH + c] = sa;
}

// ===== y' (R8-best): full-row blocks, grid (NCH, Bb), 256 thr = 16h x 16l ====
__global__ __launch_bounds__(256) void y_phase3(const bf16* __restrict__ w,
                                                const float* __restrict__ alpha_f,
                                                const float* __restrict__ S2,
                                                const float* __restrict__ SA,
                                                bf16* __restrict__ yprime) {
  const int c = blockIdx.x, b = blockIdx.y;
  const int tid = threadIdx.x, h = tid >> 4, l = tid & 15;

  // SA exclusive prefix over chunks < c: lanes split + shfl reduce
  const float* sap = SA + (size_t)(b * NHh + h) * NCH;
  float sa_part = 0.f;
  for (int cc = l; cc < c; cc += 16) sa_part += sap[cc];
  sa_part += __shfl_xor(sa_part, 1, 64);
  sa_part += __shfl_xor(sa_part, 2, 64);
  sa_part += __shfl_xor(sa_part, 4, 64);
  sa_part += __shfl_xor(sa_part, 8, 64);
  float acca = sa_part;   // uniform within the 16-lane group

  // S2 exclusive prefix over chunks < c (own 4 columns), 4-deep ILP
  const float4* p4 = (const float4*)(S2 + (((size_t)(b * NHh + h) * NCH)) * HD + l * 4);
  float4 s0 = {0,0,0,0}, s1v = {0,0,0,0}, s2v = {0,0,0,0}, s3v = {0,0,0,0};
  int cc = 0;
  for (; cc + 4 <= c; cc += 4) {
    const float4 v0 = p4[(size_t)cc * 16];
    const float4 v1 = p4[(size_t)(cc + 1) * 16];
    const float4 v2 = p4[(size_t)(cc + 2) * 16];
    const float4 v3 = p4[(size_t)(cc + 3) * 16];
    s0.x += v0.x; s0.y += v0.y; s0.z += v0.z; s0.w += v0.w;
    s1v.x += v1.x; s1v.y += v1.y; s1v.z += v1.z; s1v.w += v1.w;
    s2v.x += v2.x; s2v.y += v2.y; s2v.z += v2.z; s2v.w += v2.w;
    s3v.x += v3.x; s3v.y += v3.y; s3v.z += v3.z; s3v.w += v3.w;
  }
  for (; cc < c; cc++) {
    const float4 v0 = p4[(size_t)cc * 16];
    s0.x += v0.x; s0.y += v0.y; s0.z += v0.z; s0.w += v0.w;
  }
  float a0 = s0.x + s1v.x + s2v.x + s3v.x;
  float a1 = s0.y + s1v.y + s2v.y + s3v.y;
  float a2 = s0.z + s1v.z + s2v.z + s3v.z;
  float a3 = s0.w + s1v.w + s2v.w + s3v.w;

  const bf16* wp = w + ((size_t)(b * Tt + c * CHL)) * Dm + h * HD + l * 4;
  const float* ap = alpha_f + (size_t)(b * NHh + h) * Tt + c * CHL;
  bf16* yp = yprime + ((size_t)(b * Tt + c * CHL)) * Dm + h * HD + l * 4;
#pragma unroll 8
  for (int i = 0; i < CHL; i++) {
    const float a = ap[i];
    const ushort4 v = *(const ushort4*)(wp + (size_t)i * Dm);
    const float f0 = b2f(v.x), f1 = b2f(v.y), f2 = b2f(v.z), f3 = b2f(v.w);
    a0 += f0 * f0 * a; a1 += f1 * f1 * a; a2 += f2 * f2 * a; a3 += f3 * f3 * a;
    acca += a;
    const float rinv = frcp(acca + 1e-8f);
    const float at0 = fminf(frcp(1.f + a0 * rinv), 10000.f);
    const float at1 = fminf(frcp(1.f + a1 * rinv), 10000.f);
    const float at2 = fminf(frcp(1.f + a2 * rinv), 10000.f);
    const float at3 = fminf(frcp(1.f + a3 * rinv), 10000.f);
    ushort4 o;
    o.x = __bfloat16_as_ushort(__float2bfloat16(-f0 * a * at0));
    o.y = __bfloat16_as_ushort(__float2bfloat16(-f1 * a * at1));
    o.z = __bfloat16_as_ushort(__float2bfloat16(-f2 * a * at2));
    o.w = __bfloat16_as_ushort(__float2bfloat16(-f3 * a * at3));
    *(ushort4*)(yp + (size_t)i * Dm) = o;
  }
}

extern "C" void kernel_launch(void* const* d_in, const int* in_sizes, int n_in,
                              void* d_out, int out_size, void* d_ws, size_t ws_size,
                              hipStream_t stream) {
  const float* x     = (const float*)d_in[0];
  const float* phi   = (const float*)d_in[1];
  const float* Wattn = (const float*)d_in[2];
  const float* Wproj = (const float*)d_in[3];
  const float* gamma = (const float*)d_in[4];
  const float* temp  = (const float*)d_in[5];

  float* y_out    = (float*)d_out;                          // (B,T,D) fp32
  float* alpha_f  = y_out + (size_t)Bb * Tt * Dm;           // (B,NH,T) fp32

  char* ws = (char*)d_ws;
  bf16*  x_bf   = (bf16*)ws;  ws += (size_t)Bb * Tt * Dm * 2;         // 32 MB
  bf16*  Wa_bf  = (bf16*)ws;  ws += (size_t)Dm * Dm * 2;              // 2 MB
  bf16*  Wp_bf  = (bf16*)ws;  ws += (size_t)Dm * Dm * 2;              // 2 MB
  bf16*  w_bf   = (bf16*)ws;  ws += (size_t)Bb * Tt * Dm * 2;         // 32 MB
  float* pen    = (float*)ws; ws += (size_t)Bb * Tt * 4;              // 64 KB
  float* S1     = (float*)ws; ws += (size_t)Bb * NHh * NCH * HD * 4;  // 2 MB (raw)
  float* S2     = (float*)ws; ws += (size_t)Bb * NHh * NCH * HD * 4;  // 2 MB (raw)
  float* SA     = (float*)ws; ws += (size_t)Bb * NHh * NCH * 4;       // 32 KB (raw)
  bf16*  yprime = x_bf;  // alias: x_bf is dead after GEMM1

  static int attr_done = 0;
  if (!attr_done) {
    hipFuncSetAttribute((const void*)gemm256<true, true>,
                        hipFuncAttributeMaxDynamicSharedMemorySize, 49152);
    hipFuncSetAttribute((const void*)gemm256<false, false>,
                        hipFuncAttributeMaxDynamicSharedMemorySize, 49152);
    attr_done = 1;
  }

  const int M = Bb * Tt, N = Dm, K = Dm;
  dim3 gg((M / BM) * (N / BN)), gb(512);   // 64 x 8 = 512 blocks = 2/CU

  prep<<<dim3(1540), dim3(256), 0, stream>>>(x, Wattn, Wproj, phi, x_bf, Wa_bf, Wp_bf, pen);
  gemm256<true, true><<<gg, gb, 49152, stream>>>(x_bf, Wa_bf, (void*)w_bf, S1, M, N, K);
  mid_fused<<<dim3(NCH, Bb), dim3(256), 0, stream>>>(w_bf, S1, temp, gamma, pen,
                                                     alpha_f, S2, SA);
  y_phase3<<<dim3(NCH, Bb), dim3(256), 0, stream>>>(w_bf, alpha_f, S2, SA, yprime);
  gemm256<false, false><<<gg, gb, 49152, stream>>>(yprime, Wp_bf, (void*)y_out, nullptr, M, N, K);
}